// Round 8
// baseline (180.118 us; speedup 1.0000x reference)
//
#include <hip/hip_runtime.h>
#include <hip/hip_bf16.h>

// CACE message passing, fused. MAX_L=3 -> NL=20, N_RBF=8, RB=8, K=3 -> C=9,
// NB=5, CUTOFF=5.5, T_MP=1, MP_NORM=0.2, N=2000, E=50000. fp32 I/O.
// Round 8: k_node2's gather loop batched by 8 — r7 post-mortem: ~4000 cyc/edge
// = one congested IC/HBM round-trip per edge, serial (runtime-trip loop never
// pipelines). Now: A-mirror packed as ONE uint4 per (node,lc) (Abf4[n][180]);
// per 8-edge batch, 8 independent 16B gathers + 8 chi loads issue back-to-back
// (one latency amortized over 8 edges), consumed from zero-padded LDS est rows.
// Row (80 floats): [0:32] gw[4][8], [32:40] fr, [40:60] ang, [60:69] enc.

#define CUTF 5.5f
#define MPNORM 0.2f
#define TILE 48
#define BG 8

__constant__ int   d_DEGS[20]  = {0,1,1,1,2,2,2,2,2,2,3,3,3,3,3,3,3,3,3,3};
__constant__ float d_MULTI[20] = {1,1,1,1,1,2,2,1,2,1,1,3,3,3,6,3,1,3,3,1};

__global__ void k_count(const int* __restrict__ eidx, int* __restrict__ counts, int E) {
  int e = blockIdx.x * blockDim.x + threadIdx.x;
  if (e < E) atomicAdd(&counts[eidx[E + e]], 1);
}

// ---------------- exclusive scan of counts (N<=2048, one block of 256) -------
__global__ void k_scan(const int* __restrict__ counts, int* __restrict__ offs, int N) {
  __shared__ int part[256];
  int t = threadIdx.x;
  int local[8]; int sum = 0;
  #pragma unroll
  for (int i = 0; i < 8; i++) {
    int idx = t*8 + i;
    int v = (idx < N) ? counts[idx] : 0;
    local[i] = sum; sum += v;
  }
  part[t] = sum; __syncthreads();
  for (int d = 1; d < 256; d <<= 1) {
    int add = (t >= d) ? part[t-d] : 0;
    __syncthreads();
    part[t] += add;
    __syncthreads();
  }
  int excl = part[t] - sum;
  #pragma unroll
  for (int i = 0; i < 8; i++) {
    int idx = t*8 + i;
    if (idx < N) offs[idx] = excl + local[i];
  }
  if (t == 255) offs[N] = part[255];
}

// ------------- per-edge compute, scattered directly into CSR slot ------------
__global__ void k_edge(const float* __restrict__ pos,
                       const float* __restrict__ shifts,
                       const float* __restrict__ Wemb,
                       const float* __restrict__ Wrad,
                       const float* __restrict__ War,
                       const int* __restrict__ species,
                       const int* __restrict__ eidx,
                       const int* __restrict__ offs,
                       int* __restrict__ cursor,
                       float* __restrict__ edata,
                       int* __restrict__ esend,
                       int E) {
  __shared__ float war_s[64];
  __shared__ float wrad_s[256];   // [d][r][b]
  int t = threadIdx.x;
  if (t < 64) war_s[t] = War[t];
  wrad_s[t] = Wrad[t];            // blockDim == 256
  __syncthreads();
  int e = blockIdx.x * blockDim.x + t;
  if (e >= E) return;
  int s  = eidx[e];
  int rI = eidx[E + e];
  float vx = pos[rI*3+0] - pos[s*3+0] + shifts[e*3+0];
  float vy = pos[rI*3+1] - pos[s*3+1] + shifts[e*3+1];
  float vz = pos[rI*3+2] - pos[s*3+2] + shifts[e*3+2];
  float len = sqrtf(vx*vx + vy*vy + vz*vz);
  float inv = 1.0f / (len + 1e-9f);
  float ux = vx*inv, uy = vy*inv, uz = vz*inv;
  float uu = len * (1.0f/CUTF);
  float u2 = uu*uu, u6 = u2*u2*u2;
  float fcut = (uu < 1.0f) ? (1.0f - 28.0f*u6 + 48.0f*u6*uu - 21.0f*u6*u2) : 0.0f;
  float x = 3.14159265358979f * uu;
  float sn = sinf(x), c2 = 2.0f*cosf(x), snm1 = 0.0f;
  float pref = sqrtf(2.0f/CUTF) / (len + 1e-20f);
  float rad[8], g[8];
  #pragma unroll
  for (int k = 0; k < 8; k++) {
    rad[k] = pref * sn;
    g[k]   = rad[k] * fcut;
    float nxt = c2*sn - snm1; snm1 = sn; sn = nxt;
  }
  float v[80];
  #pragma unroll
  for (int d = 0; d < 4; d++)           // gw[d][b] = sum_r g[r]*Wrad[d][r][b]
    #pragma unroll
    for (int b = 0; b < 8; b++) {
      float a = 0.0f;
      #pragma unroll
      for (int r = 0; r < 8; r++) a += g[r] * wrad_s[d*64 + r*8 + b];
      v[d*8+b] = a;
    }
  #pragma unroll
  for (int b = 0; b < 8; b++) {         // fr = (rad @ W_ar) * fcut
    float a = 0.0f;
    #pragma unroll
    for (int k = 0; k < 8; k++) a += rad[k] * war_s[k*8+b];
    v[32+b] = a * fcut;
  }
  float px2 = ux*ux, py2 = uy*uy, pz2 = uz*uz;
  v[40] = 1.0f; v[41] = ux;     v[42] = uy;     v[43] = uz;
  v[44] = px2;  v[45] = ux*uy;  v[46] = ux*uz;  v[47] = py2;
  v[48] = uy*uz;v[49] = pz2;
  v[50] = px2*ux; v[51] = px2*uy; v[52] = px2*uz; v[53] = ux*py2;
  v[54] = ux*uy*uz; v[55] = ux*pz2; v[56] = py2*uy; v[57] = py2*uz;
  v[58] = uy*pz2; v[59] = pz2*uz;
  int zs = species[s], zr = species[rI];
  float es0 = Wemb[zs*3+0], es1 = Wemb[zs*3+1], es2 = Wemb[zs*3+2];
  float er0 = Wemb[zr*3+0], er1 = Wemb[zr*3+1], er2 = Wemb[zr*3+2];
  v[60] = es0*er0; v[61] = es0*er1; v[62] = es0*er2;
  v[63] = es1*er0; v[64] = es1*er1; v[65] = es1*er2;
  v[66] = es2*er0; v[67] = es2*er1; v[68] = es2*er2;
  #pragma unroll
  for (int w = 69; w < 80; w++) v[w] = 0.0f;
  int slot = atomicAdd(&cursor[rI], 1);
  int dst = offs[rI] + slot;
  float4* eb4 = reinterpret_cast<float4*>(edata + (size_t)dst * 80);
  #pragma unroll
  for (int w = 0; w < 20; w++)
    eb4[w] = make_float4(v[4*w], v[4*w+1], v[4*w+2], v[4*w+3]);
  esend[dst] = s;
}

// ---------------- per-node phase 1: A, Abf4, chi, B0 -------------------------
// 1 block/node, 192 threads; thread t<180 owns (l=t/9, c=t%9).
__global__ __launch_bounds__(192) void k_nodeA(
    const float* __restrict__ edata, const int* __restrict__ offs,
    const float* __restrict__ Wchi,
    float* __restrict__ A, uint4* __restrict__ Abf4,
    float* __restrict__ chi, float* __restrict__ B0, int N) {
  __shared__ float wchi_s[40];               // [b][k]
  __shared__ float Bsh[360];                 // [b][k][c]
  __shared__ __align__(16) float est[TILE*80];
  int t = threadIdx.x, n = blockIdx.x;
  for (int i = t; i < 40;  i += 192) wchi_s[i] = Wchi[i];
  for (int i = t; i < 360; i += 192) Bsh[i] = 0.0f;
  int l = t / 9, c = t - l*9;
  bool act = t < 180;
  int ll = act ? l : 0, cc = act ? c : 0;
  int deg = act ? d_DEGS[ll] : 0;
  float Ab[8];
  #pragma unroll
  for (int b = 0; b < 8; b++) Ab[b] = 0.0f;
  int start = offs[n], end = offs[n+1];
  for (int tb = start; tb < end; tb += TILE) {
    int cnt = min(TILE, end - tb);
    __syncthreads();
    const float4* src = reinterpret_cast<const float4*>(edata + (size_t)tb*80);
    float4* dst = reinterpret_cast<float4*>(est);
    for (int i = t; i < cnt*20; i += 192) dst[i] = src[i];   // coalesced
    __syncthreads();
    #pragma unroll 4
    for (int j = 0; j < cnt; j++) {
      const float* eb = est + j*80;
      float p = eb[40+ll] * eb[60+cc];
      const float4* gw4 = reinterpret_cast<const float4*>(eb + deg*8);
      float4 g0 = gw4[0], g1 = gw4[1];
      Ab[0] += p*g0.x; Ab[1] += p*g0.y; Ab[2] += p*g0.z; Ab[3] += p*g0.w;
      Ab[4] += p*g1.x; Ab[5] += p*g1.y; Ab[6] += p*g1.z; Ab[7] += p*g1.w;
    }
  }
  __syncthreads();   // Bsh zeros / wchi visible (also 0-edge nodes)
  if (act) {
    #pragma unroll
    for (int b = 0; b < 8; b++) A[(size_t)n*1440 + t*8 + b] = Ab[b];
    unsigned int pr[4];
    #pragma unroll
    for (int bp = 0; bp < 4; bp++) {
      __hip_bfloat16 blo = __float2bfloat16(Ab[2*bp]);
      __hip_bfloat16 bhi = __float2bfloat16(Ab[2*bp+1]);
      pr[bp] = (unsigned int)(*reinterpret_cast<unsigned short*>(&blo))
             | ((unsigned int)(*reinterpret_cast<unsigned short*>(&bhi)) << 16);
    }
    uint4 pk; pk.x = pr[0]; pk.y = pr[1]; pk.z = pr[2]; pk.w = pr[3];
    Abf4[(size_t)n*180 + t] = pk;            // coalesced 16B/lane
    if (l == 0) {
      #pragma unroll
      for (int b = 0; b < 8; b++) Bsh[b*45 + c] = Ab[b];
    }
    float mlt = d_MULTI[ll]; int kk = 1 + deg;
    #pragma unroll
    for (int b = 0; b < 8; b++) atomicAdd(&Bsh[b*45 + kk*9 + c], mlt*Ab[b]*Ab[b]);
  }
  __syncthreads();
  if (t < 9) {
    float s = 0.0f;
    for (int b = 0; b < 8; b++)
      #pragma unroll
      for (int kq = 0; kq < 5; kq++) s += Bsh[b*45 + kq*9 + t] * wchi_s[b*5 + kq];
    chi[n*9 + t] = s;
  }
  for (int i = t; i < 360; i += 192)
    B0[(size_t)n*360 + i] = Bsh[i];
}

// ---------------- per-node phase 2: A' = (A_ar+A_bchi)*norm + mem; out -------
__global__ __launch_bounds__(192) void k_node2(
    const float* __restrict__ edata, const int* __restrict__ esend,
    const int* __restrict__ offs, const float* __restrict__ Wmem,
    const float* __restrict__ A, const uint4* __restrict__ Abf4,
    const float* __restrict__ chi, const float* __restrict__ B0,
    float* __restrict__ out, int N) {
  __shared__ float wm_s[288];                // [deg][r][b], stride 72
  __shared__ float Bsh[360];
  __shared__ int   snd_s[TILE];
  __shared__ __align__(16) float est[TILE*80];
  int t = threadIdx.x, n = blockIdx.x;
  for (int i = t; i < 256; i += 192) { int d = i >> 6, rm = i & 63; wm_s[d*72+rm] = Wmem[i]; }
  for (int i = t; i < 360; i += 192) Bsh[i] = 0.0f;
  int l = t / 9, c = t - l*9;
  bool act = t < 180;
  int ll = act ? l : 0, cc = act ? c : 0;
  int tt = act ? t : 0;
  int deg = act ? d_DEGS[ll] : 0;
  float Sb[8], ARacc[8];
  #pragma unroll
  for (int b = 0; b < 8; b++) { Sb[b] = 0.0f; ARacc[b] = 0.0f; }
  int start = offs[n], end = offs[n+1];
  for (int tb = start; tb < end; tb += TILE) {
    int cnt = min(TILE, end - tb);
    int cntp = (cnt + BG - 1) & ~(BG - 1);           // pad to multiple of 8
    __syncthreads();
    const float4* src = reinterpret_cast<const float4*>(edata + (size_t)tb*80);
    float4* dst = reinterpret_cast<float4*>(est);
    for (int i = t; i < cnt*20; i += 192) dst[i] = src[i];
    for (int i = t; i < (cntp-cnt)*20; i += 192)     // zero-pad rows
      dst[cnt*20 + i] = make_float4(0,0,0,0);
    for (int i = t; i < cntp; i += 192)
      snd_s[i] = (i < cnt) ? esend[tb + i] : 0;
    __syncthreads();
    for (int g = 0; g < cntp; g += BG) {
      // batch: 8 independent gathers issued back-to-back (one latency for 8)
      int sd[BG];
      #pragma unroll
      for (int u = 0; u < BG; u++) sd[u] = snd_s[g+u];
      uint4 q[BG]; float ch[BG];
      #pragma unroll
      for (int u = 0; u < BG; u++) {
        q[u]  = Abf4[(size_t)sd[u]*180 + tt];
        ch[u] = chi[sd[u]*9 + cc];
      }
      #pragma unroll
      for (int u = 0; u < BG; u++) {
        const float* eb = est + (g+u)*80;
        float pch = eb[40+ll] * eb[60+cc] * ch[u];
        const float4* gw4 = reinterpret_cast<const float4*>(eb + deg*8);
        float4 g0 = gw4[0], g1 = gw4[1];
        Sb[0] += pch*g0.x; Sb[1] += pch*g0.y; Sb[2] += pch*g0.z; Sb[3] += pch*g0.w;
        Sb[4] += pch*g1.x; Sb[5] += pch*g1.y; Sb[6] += pch*g1.z; Sb[7] += pch*g1.w;
        const float4* fr4 = reinterpret_cast<const float4*>(eb + 32);
        float4 f0 = fr4[0], f1 = fr4[1];
        float a0 = __uint_as_float(q[u].x << 16), a1 = __uint_as_float(q[u].x & 0xffff0000u);
        float a2 = __uint_as_float(q[u].y << 16), a3 = __uint_as_float(q[u].y & 0xffff0000u);
        float a4 = __uint_as_float(q[u].z << 16), a5 = __uint_as_float(q[u].z & 0xffff0000u);
        float a6 = __uint_as_float(q[u].w << 16), a7 = __uint_as_float(q[u].w & 0xffff0000u);
        ARacc[0] += a0*f0.x; ARacc[1] += a1*f0.y;
        ARacc[2] += a2*f0.z; ARacc[3] += a3*f0.w;
        ARacc[4] += a4*f1.x; ARacc[5] += a5*f1.y;
        ARacc[6] += a6*f1.z; ARacc[7] += a7*f1.w;
      }
    }
  }
  __syncthreads();   // wm_s/Bsh zeros visible (also 0-edge nodes)
  if (act) {
    const float* wmp = &wm_s[deg*72];
    const float* aop = A + (size_t)n*1440 + t*8;
    float aown[8];
    #pragma unroll
    for (int r = 0; r < 8; r++) aown[r] = aop[r];
    float newA[8];
    #pragma unroll
    for (int b = 0; b < 8; b++) {
      float mem = 0.0f;
      #pragma unroll
      for (int r = 0; r < 8; r++) mem += aown[r]*wmp[r*8+b];
      newA[b] = (ARacc[b] + Sb[b])*MPNORM + mem;
    }
    if (l == 0) {
      #pragma unroll
      for (int b = 0; b < 8; b++) Bsh[b*45 + c] = newA[b];
    }
    float mlt = d_MULTI[ll]; int kk = 1 + deg;
    #pragma unroll
    for (int b = 0; b < 8; b++) atomicAdd(&Bsh[b*45 + kk*9 + c], mlt*newA[b]*newA[b]);
  }
  __syncthreads();
  float2* out2 = reinterpret_cast<float2*>(out);
  for (int i = t; i < 360; i += 192) {
    float2 pk; pk.x = B0[(size_t)n*360 + i]; pk.y = Bsh[i];
    out2[(size_t)n*360 + i] = pk;
  }
}

extern "C" void kernel_launch(void* const* d_in, const int* in_sizes, int n_in,
                              void* d_out, int out_size, void* d_ws, size_t ws_size,
                              hipStream_t stream) {
  const float* pos    = (const float*)d_in[0];
  const float* shifts = (const float*)d_in[1];
  const float* Wemb   = (const float*)d_in[2];
  const float* Wrad   = (const float*)d_in[3];
  const float* Wmem   = (const float*)d_in[4];
  const float* War    = (const float*)d_in[5];
  const float* Wchi   = (const float*)d_in[6];
  const int* species = (const int*)d_in[7];
  const int* eidx    = (const int*)d_in[8];
  float* out = (float*)d_out;
  int N = in_sizes[7];
  int E = in_sizes[8] / 2;

  char* base = (char*)d_ws;
  size_t off = 0;
  float* edata = (float*)(base + off); off += (size_t)E*80*4;          // 16 MB (CSR-sorted)
  float* A     = (float*)(base + off); off += (size_t)N*1440*4;        // 11.52 MB
  uint4* Abf4  = (uint4*)(base + off); off += (size_t)N*180*16;        // 5.76 MB
  float* chi   = (float*)(base + off); off += (size_t)N*9*4;
  float* B0    = (float*)(base + off); off += (size_t)N*360*4;         // 2.88 MB
  int* counts  = (int*)(base + off);   off += (size_t)N*4;
  int* cursor  = (int*)(base + off);   off += (size_t)N*4;
  int* offs    = (int*)(base + off);   off += (((size_t)(N+1)*4) + 15) & ~(size_t)15;
  int* esend   = (int*)(base + off);   off += (size_t)E*4;

  hipMemsetAsync(counts, 0, (size_t)N*2*4, stream);  // counts + cursor (adjacent)
  int eb = (E + 255) / 256;
  k_count<<<eb, 256, 0, stream>>>(eidx, counts, E);
  k_scan<<<1, 256, 0, stream>>>(counts, offs, N);
  k_edge<<<eb, 256, 0, stream>>>(pos, shifts, Wemb, Wrad, War, species, eidx, offs,
                                 cursor, edata, esend, E);
  k_nodeA<<<N, 192, 0, stream>>>(edata, offs, Wchi, A, Abf4, chi, B0, N);
  k_node2<<<N, 192, 0, stream>>>(edata, esend, offs, Wmem, A, Abf4, chi, B0, out, N);
}

// Round 10
// 173.479 us; speedup vs baseline: 1.0383x; 1.0383x over previous
//
#include <hip/hip_runtime.h>
#include <hip/hip_bf16.h>

// CACE message passing, fused. MAX_L=3 -> NL=20, N_RBF=8, RB=8, K=3 -> C=9,
// NB=5, CUTOFF=5.5, T_MP=1, MP_NORM=0.2, N=2000, E=50000. fp32 I/O.
// Round 10: split kernels (cooperative launch fails under graph capture, r9).
// k_node2 uses cp.async-style BULK LDS STAGING of the A-mirror gather: per
// 8-edge batch, 1440 independent coalesced 16B loads stage all 8 gathered
// rows into LDS (structural MLP, no register-pressure gamble — r8's register
// batching was serialized by the compiler at VGPR=48), then consumption is
// LDS-only. Gather wall is compulsory per-XCD fill of the 5.76MB table
// (FETCH ~= 8 x 5.76MB across r3-r8); staging attacks the latency, not bytes.
// Row (80 floats): [0:32] gw[4][8], [32:40] fr, [40:60] ang, [60:69] enc.

#define CUTF 5.5f
#define MPNORM 0.2f
#define TILE 48
#define BG 8

__constant__ int   d_DEGS[20]  = {0,1,1,1,2,2,2,2,2,2,3,3,3,3,3,3,3,3,3,3};
__constant__ float d_MULTI[20] = {1,1,1,1,1,2,2,1,2,1,1,3,3,3,6,3,1,3,3,1};

__global__ void k_count(const int* __restrict__ eidx, int* __restrict__ counts, int E) {
  int e = blockIdx.x * blockDim.x + threadIdx.x;
  if (e < E) atomicAdd(&counts[eidx[E + e]], 1);
}

// ---------------- exclusive scan of counts (N<=2048, one block of 256) -------
__global__ void k_scan(const int* __restrict__ counts, int* __restrict__ offs, int N) {
  __shared__ int part[256];
  int t = threadIdx.x;
  int local[8]; int sum = 0;
  #pragma unroll
  for (int i = 0; i < 8; i++) {
    int idx = t*8 + i;
    int v = (idx < N) ? counts[idx] : 0;
    local[i] = sum; sum += v;
  }
  part[t] = sum; __syncthreads();
  for (int d = 1; d < 256; d <<= 1) {
    int add = (t >= d) ? part[t-d] : 0;
    __syncthreads();
    part[t] += add;
    __syncthreads();
  }
  int excl = part[t] - sum;
  #pragma unroll
  for (int i = 0; i < 8; i++) {
    int idx = t*8 + i;
    if (idx < N) offs[idx] = excl + local[i];
  }
  if (t == 255) offs[N] = part[255];
}

// ------------- per-edge compute, scattered directly into CSR slot ------------
__global__ void k_edge(const float* __restrict__ pos,
                       const float* __restrict__ shifts,
                       const float* __restrict__ Wemb,
                       const float* __restrict__ Wrad,
                       const float* __restrict__ War,
                       const int* __restrict__ species,
                       const int* __restrict__ eidx,
                       const int* __restrict__ offs,
                       int* __restrict__ cursor,
                       float* __restrict__ edata,
                       int* __restrict__ esend,
                       int E) {
  __shared__ float war_s[64];
  __shared__ float wrad_s[256];   // [d][r][b]
  int t = threadIdx.x;
  if (t < 64) war_s[t] = War[t];
  wrad_s[t] = Wrad[t];            // blockDim == 256
  __syncthreads();
  int e = blockIdx.x * blockDim.x + t;
  if (e >= E) return;
  int s  = eidx[e];
  int rI = eidx[E + e];
  float vx = pos[rI*3+0] - pos[s*3+0] + shifts[e*3+0];
  float vy = pos[rI*3+1] - pos[s*3+1] + shifts[e*3+1];
  float vz = pos[rI*3+2] - pos[s*3+2] + shifts[e*3+2];
  float len = sqrtf(vx*vx + vy*vy + vz*vz);
  float inv = 1.0f / (len + 1e-9f);
  float ux = vx*inv, uy = vy*inv, uz = vz*inv;
  float uu = len * (1.0f/CUTF);
  float u2 = uu*uu, u6 = u2*u2*u2;
  float fcut = (uu < 1.0f) ? (1.0f - 28.0f*u6 + 48.0f*u6*uu - 21.0f*u6*u2) : 0.0f;
  float x = 3.14159265358979f * uu;
  float sn = sinf(x), c2 = 2.0f*cosf(x), snm1 = 0.0f;
  float pref = sqrtf(2.0f/CUTF) / (len + 1e-20f);
  float rad[8], g[8];
  #pragma unroll
  for (int k = 0; k < 8; k++) {
    rad[k] = pref * sn;
    g[k]   = rad[k] * fcut;
    float nxt = c2*sn - snm1; snm1 = sn; sn = nxt;
  }
  float v[80];
  #pragma unroll
  for (int d = 0; d < 4; d++)           // gw[d][b] = sum_r g[r]*Wrad[d][r][b]
    #pragma unroll
    for (int b = 0; b < 8; b++) {
      float a = 0.0f;
      #pragma unroll
      for (int r = 0; r < 8; r++) a += g[r] * wrad_s[d*64 + r*8 + b];
      v[d*8+b] = a;
    }
  #pragma unroll
  for (int b = 0; b < 8; b++) {         // fr = (rad @ W_ar) * fcut
    float a = 0.0f;
    #pragma unroll
    for (int k = 0; k < 8; k++) a += rad[k] * war_s[k*8+b];
    v[32+b] = a * fcut;
  }
  float px2 = ux*ux, py2 = uy*uy, pz2 = uz*uz;
  v[40] = 1.0f; v[41] = ux;     v[42] = uy;     v[43] = uz;
  v[44] = px2;  v[45] = ux*uy;  v[46] = ux*uz;  v[47] = py2;
  v[48] = uy*uz;v[49] = pz2;
  v[50] = px2*ux; v[51] = px2*uy; v[52] = px2*uz; v[53] = ux*py2;
  v[54] = ux*uy*uz; v[55] = ux*pz2; v[56] = py2*uy; v[57] = py2*uz;
  v[58] = uy*pz2; v[59] = pz2*uz;
  int zs = species[s], zr = species[rI];
  float es0 = Wemb[zs*3+0], es1 = Wemb[zs*3+1], es2 = Wemb[zs*3+2];
  float er0 = Wemb[zr*3+0], er1 = Wemb[zr*3+1], er2 = Wemb[zr*3+2];
  v[60] = es0*er0; v[61] = es0*er1; v[62] = es0*er2;
  v[63] = es1*er0; v[64] = es1*er1; v[65] = es1*er2;
  v[66] = es2*er0; v[67] = es2*er1; v[68] = es2*er2;
  #pragma unroll
  for (int w = 69; w < 80; w++) v[w] = 0.0f;
  int slot = atomicAdd(&cursor[rI], 1);
  int dst = offs[rI] + slot;
  float4* eb4 = reinterpret_cast<float4*>(edata + (size_t)dst * 80);
  #pragma unroll
  for (int w = 0; w < 20; w++)
    eb4[w] = make_float4(v[4*w], v[4*w+1], v[4*w+2], v[4*w+3]);
  esend[dst] = s;
}

// ---------------- per-node phase 1: A, Abf4, chi, B0 -------------------------
// 1 block/node, 192 threads; thread t<180 owns (l=t/9, c=t%9).
__global__ __launch_bounds__(192) void k_nodeA(
    const float* __restrict__ edata, const int* __restrict__ offs,
    const float* __restrict__ Wchi,
    float* __restrict__ A, uint4* __restrict__ Abf4,
    float* __restrict__ chi, float* __restrict__ B0, int N) {
  __shared__ float wchi_s[40];               // [b][k]
  __shared__ float Bsh[360];                 // [b][k][c]
  __shared__ __align__(16) float est[TILE*80];
  int t = threadIdx.x, n = blockIdx.x;
  for (int i = t; i < 40;  i += 192) wchi_s[i] = Wchi[i];
  for (int i = t; i < 360; i += 192) Bsh[i] = 0.0f;
  int l = t / 9, c = t - l*9;
  bool act = t < 180;
  int ll = act ? l : 0, cc = act ? c : 0;
  int deg = act ? d_DEGS[ll] : 0;
  float Ab[8];
  #pragma unroll
  for (int b = 0; b < 8; b++) Ab[b] = 0.0f;
  int start = offs[n], end = offs[n+1];
  for (int tb = start; tb < end; tb += TILE) {
    int cnt = min(TILE, end - tb);
    __syncthreads();
    const float4* src = reinterpret_cast<const float4*>(edata + (size_t)tb*80);
    float4* dst = reinterpret_cast<float4*>(est);
    for (int i = t; i < cnt*20; i += 192) dst[i] = src[i];   // coalesced
    __syncthreads();
    #pragma unroll 4
    for (int j = 0; j < cnt; j++) {
      const float* eb = est + j*80;
      float p = eb[40+ll] * eb[60+cc];
      const float4* gw4 = reinterpret_cast<const float4*>(eb + deg*8);
      float4 g0 = gw4[0], g1 = gw4[1];
      Ab[0] += p*g0.x; Ab[1] += p*g0.y; Ab[2] += p*g0.z; Ab[3] += p*g0.w;
      Ab[4] += p*g1.x; Ab[5] += p*g1.y; Ab[6] += p*g1.z; Ab[7] += p*g1.w;
    }
  }
  __syncthreads();   // Bsh zeros / wchi visible (also 0-edge nodes)
  if (act) {
    #pragma unroll
    for (int b = 0; b < 8; b++) A[(size_t)n*1440 + t*8 + b] = Ab[b];
    unsigned int pr[4];
    #pragma unroll
    for (int bp = 0; bp < 4; bp++) {
      __hip_bfloat16 blo = __float2bfloat16(Ab[2*bp]);
      __hip_bfloat16 bhi = __float2bfloat16(Ab[2*bp+1]);
      pr[bp] = (unsigned int)(*reinterpret_cast<unsigned short*>(&blo))
             | ((unsigned int)(*reinterpret_cast<unsigned short*>(&bhi)) << 16);
    }
    uint4 pk; pk.x = pr[0]; pk.y = pr[1]; pk.z = pr[2]; pk.w = pr[3];
    Abf4[(size_t)n*180 + t] = pk;            // coalesced 16B/lane
    if (l == 0) {
      #pragma unroll
      for (int b = 0; b < 8; b++) Bsh[b*45 + c] = Ab[b];
    }
    float mlt = d_MULTI[ll]; int kk = 1 + deg;
    #pragma unroll
    for (int b = 0; b < 8; b++) atomicAdd(&Bsh[b*45 + kk*9 + c], mlt*Ab[b]*Ab[b]);
  }
  __syncthreads();
  if (t < 9) {
    float s = 0.0f;
    for (int b = 0; b < 8; b++)
      #pragma unroll
      for (int kq = 0; kq < 5; kq++) s += Bsh[b*45 + kq*9 + t] * wchi_s[b*5 + kq];
    chi[n*9 + t] = s;
  }
  for (int i = t; i < 360; i += 192)
    B0[(size_t)n*360 + i] = Bsh[i];
}

// ---------------- per-node phase 2: A' = (A_ar+A_bchi)*norm + mem; out -------
// 8-edge batches; A-mirror rows bulk-staged into LDS (1440 independent
// coalesced 16B loads per batch = structural MLP), consumption LDS-only.
__global__ __launch_bounds__(192) void k_node2(
    const float* __restrict__ edata, const int* __restrict__ esend,
    const int* __restrict__ offs, const float* __restrict__ Wmem,
    const float* __restrict__ A, const uint4* __restrict__ Abf4,
    const float* __restrict__ chi, const float* __restrict__ B0,
    float* __restrict__ out, int N) {
  __shared__ float wm_s[288];                // [deg][r][b], stride 72
  __shared__ float Bsh[360];
  __shared__ int   snd_s[BG];
  __shared__ float chi_s[BG*9];
  __shared__ __align__(16) float est[BG*80];    // 2.56 KB
  __shared__ uint4 stg[BG*180];                 // 23 KB staged A-mirror rows
  int t = threadIdx.x, n = blockIdx.x;
  for (int i = t; i < 256; i += 192) { int d = i >> 6, rm = i & 63; wm_s[d*72+rm] = Wmem[i]; }
  for (int i = t; i < 360; i += 192) Bsh[i] = 0.0f;
  int l = t / 9, c = t - l*9;
  bool act = t < 180;
  int ll = act ? l : 0, cc = act ? c : 0;
  int tt = act ? t : 0;
  int deg = act ? d_DEGS[ll] : 0;
  float Sb[8], AR[8];
  #pragma unroll
  for (int b = 0; b < 8; b++) { Sb[b] = 0.0f; AR[b] = 0.0f; }
  int start = offs[n], end = offs[n+1];
  for (int j0 = start; j0 < end; j0 += BG) {
    int cb = min(BG, end - j0);
    __syncthreads();                           // prev batch consumers done
    const float4* src = reinterpret_cast<const float4*>(edata + (size_t)j0*80);
    float4* dst = reinterpret_cast<float4*>(est);
    for (int i = t; i < cb*20; i += 192) dst[i] = src[i];      // coalesced est
    if (t < BG) snd_s[t] = (t < cb) ? esend[j0 + t] : esend[j0];
    __syncthreads();                           // est + snd visible
    #pragma unroll
    for (int u = 0; u < BG; u++) {             // bulk stage: 8 coalesced rows
      int sr = snd_s[u];
      if (t < 180) stg[u*180 + t] = Abf4[(size_t)sr*180 + t];
    }
    if (t < BG*9) { int u = t / 9; chi_s[t] = chi[snd_s[u]*9 + (t - u*9)]; }
    __syncthreads();                           // stage visible
    for (int u = 0; u < cb; u++) {             // LDS-only consumption
      const float* eb = est + u*80;
      float ch = chi_s[u*9 + cc];
      float pch = eb[40+ll] * eb[60+cc] * ch;
      const float4* gw4 = reinterpret_cast<const float4*>(eb + deg*8);
      float4 g0 = gw4[0], g1 = gw4[1];
      Sb[0] += pch*g0.x; Sb[1] += pch*g0.y; Sb[2] += pch*g0.z; Sb[3] += pch*g0.w;
      Sb[4] += pch*g1.x; Sb[5] += pch*g1.y; Sb[6] += pch*g1.z; Sb[7] += pch*g1.w;
      const float4* fr4 = reinterpret_cast<const float4*>(eb + 32);
      float4 f0 = fr4[0], f1 = fr4[1];
      uint4 q = stg[u*180 + tt];
      float a0 = __uint_as_float(q.x << 16), a1 = __uint_as_float(q.x & 0xffff0000u);
      float a2 = __uint_as_float(q.y << 16), a3 = __uint_as_float(q.y & 0xffff0000u);
      float a4 = __uint_as_float(q.z << 16), a5 = __uint_as_float(q.z & 0xffff0000u);
      float a6 = __uint_as_float(q.w << 16), a7 = __uint_as_float(q.w & 0xffff0000u);
      AR[0] += a0*f0.x; AR[1] += a1*f0.y; AR[2] += a2*f0.z; AR[3] += a3*f0.w;
      AR[4] += a4*f1.x; AR[5] += a5*f1.y; AR[6] += a6*f1.z; AR[7] += a7*f1.w;
    }
  }
  __syncthreads();   // wm_s/Bsh zeros visible (also 0-edge nodes)
  if (act) {
    const float* wmp = &wm_s[deg*72];
    const float* aop = A + (size_t)n*1440 + t*8;
    float aown[8];
    #pragma unroll
    for (int r = 0; r < 8; r++) aown[r] = aop[r];
    float newA[8];
    #pragma unroll
    for (int b = 0; b < 8; b++) {
      float mem = 0.0f;
      #pragma unroll
      for (int r = 0; r < 8; r++) mem += aown[r]*wmp[r*8+b];
      newA[b] = (AR[b] + Sb[b])*MPNORM + mem;
    }
    if (l == 0) {
      #pragma unroll
      for (int b = 0; b < 8; b++) Bsh[b*45 + c] = newA[b];
    }
    float mlt = d_MULTI[ll]; int kk = 1 + deg;
    #pragma unroll
    for (int b = 0; b < 8; b++) atomicAdd(&Bsh[b*45 + kk*9 + c], mlt*newA[b]*newA[b]);
  }
  __syncthreads();
  float2* out2 = reinterpret_cast<float2*>(out);
  for (int i = t; i < 360; i += 192) {
    float2 pk; pk.x = B0[(size_t)n*360 + i]; pk.y = Bsh[i];
    out2[(size_t)n*360 + i] = pk;
  }
}

extern "C" void kernel_launch(void* const* d_in, const int* in_sizes, int n_in,
                              void* d_out, int out_size, void* d_ws, size_t ws_size,
                              hipStream_t stream) {
  const float* pos    = (const float*)d_in[0];
  const float* shifts = (const float*)d_in[1];
  const float* Wemb   = (const float*)d_in[2];
  const float* Wrad   = (const float*)d_in[3];
  const float* Wmem   = (const float*)d_in[4];
  const float* War    = (const float*)d_in[5];
  const float* Wchi   = (const float*)d_in[6];
  const int* species = (const int*)d_in[7];
  const int* eidx    = (const int*)d_in[8];
  float* out = (float*)d_out;
  int N = in_sizes[7];
  int E = in_sizes[8] / 2;

  char* base = (char*)d_ws;
  size_t off = 0;
  float* edata = (float*)(base + off); off += (size_t)E*80*4;          // 16 MB (CSR-sorted)
  float* A     = (float*)(base + off); off += (size_t)N*1440*4;        // 11.52 MB
  uint4* Abf4  = (uint4*)(base + off); off += (size_t)N*180*16;        // 5.76 MB
  float* chi   = (float*)(base + off); off += (size_t)N*9*4;
  float* B0    = (float*)(base + off); off += (size_t)N*360*4;         // 2.88 MB
  int* counts  = (int*)(base + off);   off += (size_t)N*4;
  int* cursor  = (int*)(base + off);   off += (size_t)N*4;
  int* offs    = (int*)(base + off);   off += (((size_t)(N+1)*4) + 15) & ~(size_t)15;
  int* esend   = (int*)(base + off);   off += (size_t)E*4;

  hipMemsetAsync(counts, 0, (size_t)N*2*4, stream);  // counts + cursor (adjacent)
  int eb = (E + 255) / 256;
  k_count<<<eb, 256, 0, stream>>>(eidx, counts, E);
  k_scan<<<1, 256, 0, stream>>>(counts, offs, N);
  k_edge<<<eb, 256, 0, stream>>>(pos, shifts, Wemb, Wrad, War, species, eidx, offs,
                                 cursor, edata, esend, E);
  k_nodeA<<<N, 192, 0, stream>>>(edata, offs, Wchi, A, Abf4, chi, B0, N);
  k_node2<<<N, 192, 0, stream>>>(edata, esend, offs, Wmem, A, Abf4, chi, B0, out, N);
}